// Round 4
// baseline (2441.342 us; speedup 1.0000x reference)
//
#include <hip/hip_runtime.h>

#define E_CNT 32768
#define V_CNT 98304
#define D_ 128
#define VOCAB_ 2000
#define ITERS_ 6

typedef unsigned short u16;
typedef __attribute__((ext_vector_type(8))) short bf16x8;
typedef __attribute__((ext_vector_type(8))) unsigned short u16x8;
typedef __attribute__((ext_vector_type(4))) float f32x4;

__device__ __forceinline__ f32x4 MF(bf16x8 a, bf16x8 b, f32x4 c) {
    return __builtin_amdgcn_mfma_f32_16x16x32_bf16(a, b, c, 0, 0, 0);
}
__device__ __forceinline__ bf16x8 ld8(const u16* p) { return *reinterpret_cast<const bf16x8*>(p); }

__device__ __forceinline__ u16 f2bf(float x) {
    unsigned u = __float_as_uint(x);
    return (u16)((u + 0x7FFFu + ((u >> 16) & 1u)) >> 16);
}
__device__ __forceinline__ float bf2f(u16 h) { return __uint_as_float(((unsigned)h) << 16); }
__device__ __forceinline__ float sigmoid_f(float x) { return 1.0f / (1.0f + __expf(-x)); }
__device__ __forceinline__ float tanh_f(float x) {
    float ax = fabsf(x);
    float t = 1.0f - 2.0f / (__expf(2.0f * ax) + 1.0f);
    return copysignf(t, x);
}

// LDS swizzle (u16-unit index): XOR (row&7)<<3 u16s == <<4 bytes.
// Breaks the row-stride ≡ 0 (mod 128B) 16-way bank conflict on ds_read_b128.
__device__ __forceinline__ int swzHV(int row, int col) { return (row * 384 + col) ^ ((row & 7) << 3); }
__device__ __forceinline__ int swzHE(int row, int col) { return (row * 128 + col) ^ ((row & 7) << 3); }

__global__ void detect_mask_kernel(const unsigned int* __restrict__ m, int* __restrict__ flag) {
    int i = blockIdx.x * 256 + threadIdx.x;
    if (i < 4096 && m[i] > 1u) atomicOr(flag, 1);
}

// Pack weights into MFMA B-fragment order (bf16 hi/lo split).
__global__ void prep_kernel(
    const float* __restrict__ Wih_v2e, const float* __restrict__ Whh_v2e,
    const float* __restrict__ bih_v2e, const float* __restrict__ bhh_v2e,
    const float* __restrict__ Wih_e2v, const float* __restrict__ Whh_e2v,
    const float* __restrict__ bih_e2v, const float* __restrict__ bhh_e2v,
    const float* __restrict__ out_w,
    u16* __restrict__ WvFh, u16* __restrict__ WvFl,
    u16* __restrict__ WeFh, u16* __restrict__ WeFl,
    u16* __restrict__ OwFh, u16* __restrict__ OwFl,
    float* __restrict__ bv, float* __restrict__ be)
{
    int idx = blockIdx.x * 256 + threadIdx.x;
    if (idx < 262144) {
        const int r = idx & 7, l = (idx >> 3) & 63, t = idx >> 9;
        const int kk = t & 15, nt = t >> 4;
        const int j = nt * 16 + (l & 15);
        const int k = kk * 32 + (l >> 4) * 8 + r;
        const float w = (k < 384) ? Wih_v2e[j * 384 + k] : Whh_v2e[j * 128 + (k - 384)];
        const u16 h = f2bf(w);
        WvFh[idx] = h; WvFl[idx] = f2bf(w - bf2f(h));
        return;
    }
    idx -= 262144;
    if (idx < 393216) {
        const int r = idx & 7, l = (idx >> 3) & 63, t = idx >> 9;  // t < 768
        const int kk = t & 7, nt = (t >> 3) & 31, p = t >> 8;
        const int j = nt * 16 + (l & 15);
        const int k = kk * 32 + (l >> 4) * 8 + r;
        const float w = (k < 128) ? Wih_e2v[(p * 512 + j) * 128 + k]
                                  : Whh_e2v[(p * 512 + j) * 128 + (k - 128)];
        const u16 h = f2bf(w);
        WeFh[idx] = h; WeFl[idx] = f2bf(w - bf2f(h));
        return;
    }
    idx -= 393216;
    if (idx < 256000) {
        const int r = idx & 7, l = (idx >> 3) & 63, t = idx >> 9;  // t < 500
        const int kk = t & 3, nt = t >> 2;
        const int j = nt * 16 + (l & 15);
        const int k = kk * 32 + (l >> 4) * 8 + r;
        const float w = out_w[j * 128 + k];
        const u16 h = f2bf(w);
        OwFh[idx] = h; OwFl[idx] = f2bf(w - bf2f(h));
        return;
    }
    idx -= 256000;
    if (idx < 512) { bv[idx] = bih_v2e[idx] + bhh_v2e[idx]; return; }
    idx -= 512;
    if (idx < 1536) { be[idx] = bih_e2v[idx] + bhh_e2v[idx]; return; }
}

// Persistent fused kernel: block = 512 threads (8 waves) owns 64 edges for all 6 iterations.
// LDS: h_v hi/lo [64][384] + h_e hi/lo [64][128] (XOR-swizzled). c_v/c_e in registers.
// amdgpu_waves_per_eu(2,2): 128KB LDS -> 1 block/CU anyway; pin 2 waves/EU so the
// register budget is 256/wave (live state ~207) -> no scratch spills (round-3 bug:
// compiler targeted 128 VGPR with dynamic LDS and spilled the 64-f32 c-state, 800 MB traffic).
__global__ __launch_bounds__(512) __attribute__((amdgpu_waves_per_eu(2, 2)))
void fused_kernel(
    const int* __restrict__ x_v,
    const float* __restrict__ emb,
    const float* __restrict__ eiw, const float* __restrict__ eib,
    const u16* __restrict__ WvFh, const u16* __restrict__ WvFl,
    const u16* __restrict__ WeFh, const u16* __restrict__ WeFl,
    const float* __restrict__ bv, const float* __restrict__ be,
    const void* __restrict__ mask, const int* __restrict__ flagp,
    u16* __restrict__ hvOutH, u16* __restrict__ hvOutL)
{
    extern __shared__ u16 lds[];
    u16* HVh = lds;                // 24576 u16
    u16* HVl = lds + 24576;        // 24576
    u16* HEh = lds + 49152;        // 8192
    u16* HEl = lds + 57344;        // 8192  -> 131072 B total

    const int tid = threadIdx.x;
    const int w = tid >> 6, l = tid & 63;
    const int lr = l & 15, lk = l >> 4;
    const int e0 = blockIdx.x * 64;

    // ---- init h_v from embeddings (split hi/lo into LDS)
    for (int i = tid; i < 64 * 48; i += 512) {
        const int row = i / 48, seg = i % 48;
        const int col0 = seg * 8;
        int id = x_v[(e0 + row) * 3 + (col0 >> 7)];
        if (id < 0 || id > VOCAB_) id = VOCAB_;
        const float* s = emb + id * D_ + (col0 & 127);
        float4 a = *(const float4*)s, b = *(const float4*)(s + 4);
        float xs[8] = {a.x, a.y, a.z, a.w, b.x, b.y, b.z, b.w};
        u16x8 H, L;
        #pragma unroll
        for (int j = 0; j < 8; ++j) { H[j] = f2bf(xs[j]); L[j] = f2bf(xs[j] - bf2f(H[j])); }
        const int si = swzHV(row, col0);
        *(u16x8*)&HVh[si] = H;
        *(u16x8*)&HVl[si] = L;
    }
    // ---- init h_e (same vector for every edge)
    for (int i = tid; i < 64 * 16; i += 512) {
        const int row = i / 16, col0 = (i % 16) * 8;
        u16x8 H, L;
        #pragma unroll
        for (int j = 0; j < 8; ++j) {
            const float x = eiw[col0 + j] + eib[col0 + j];
            H[j] = f2bf(x); L[j] = f2bf(x - bf2f(H[j]));
        }
        const int si = swzHE(row, col0);
        *(u16x8*)&HEh[si] = H;
        *(u16x8*)&HEl[si] = L;
    }

    // ---- per-lane constants: mask bits, biases, c-state
    const int isByte = *flagp;
    unsigned mbits[3];
    #pragma unroll
    for (int p = 0; p < 3; ++p) {
        unsigned mb = 0;
        #pragma unroll
        for (int mt = 0; mt < 4; ++mt)
            #pragma unroll
            for (int r = 0; r < 4; ++r) {
                const int v = (e0 + mt * 16 + lk * 4 + r) * 3 + p;
                const bool m = isByte ? (((const unsigned char*)mask)[v] != 0)
                                      : (((const int*)mask)[v] != 0);
                mb |= (unsigned)m << (mt * 4 + r);
            }
        mbits[p] = mb;
    }
    const int d = w * 16 + lr;
    const float bvi = bv[d], bvf = bv[128 + d], bvg = bv[256 + d], bvo = bv[384 + d];
    float bei[3], bef[3], beg[3], beo[3];
    #pragma unroll
    for (int p = 0; p < 3; ++p) {
        bei[p] = be[p * 512 + d];       bef[p] = be[p * 512 + 128 + d];
        beg[p] = be[p * 512 + 256 + d]; beo[p] = be[p * 512 + 384 + d];
    }
    float ce[4][4], cv[3][4][4];
    #pragma unroll
    for (int mt = 0; mt < 4; ++mt)
        #pragma unroll
        for (int r = 0; r < 4; ++r) {
            ce[mt][r] = 0.0f;
            #pragma unroll
            for (int p = 0; p < 3; ++p) cv[p][mt][r] = 0.0f;
        }

    __syncthreads();

// term-outer / mt-inner: same-accumulator MFMA distance = 4 (covers MFMA latency)
#define GEMM_STEP(WH, WL, FBASE)                                         \
    { _Pragma("unroll")                                                  \
      for (int g = 0; g < 4; ++g) {                                      \
          const int fb = (FBASE);                                        \
          bf16x8 Bh = ld8(WH + fb), Bl = ld8(WL + fb);                   \
          _Pragma("unroll")                                              \
          for (int mt = 0; mt < 4; ++mt) acc[mt][g] = MF(Ah[mt], Bh, acc[mt][g]); \
          _Pragma("unroll")                                              \
          for (int mt = 0; mt < 4; ++mt) acc[mt][g] = MF(Al[mt], Bh, acc[mt][g]); \
          _Pragma("unroll")                                              \
          for (int mt = 0; mt < 4; ++mt) acc[mt][g] = MF(Ah[mt], Bl, acc[mt][g]); \
      } }

    for (int it = 0; it < ITERS_; ++it) {
        // ======== vertex -> edge ========
        {
            f32x4 acc[4][4];
            #pragma unroll
            for (int mt = 0; mt < 4; ++mt)
                #pragma unroll
                for (int g = 0; g < 4; ++g) acc[mt][g] = (f32x4)0.0f;

            #pragma unroll 2
            for (int kk = 0; kk < 12; ++kk) {
                bf16x8 Ah[4], Al[4];
                #pragma unroll
                for (int mt = 0; mt < 4; ++mt) {
                    const int si = swzHV(mt * 16 + lr, kk * 32 + lk * 8);
                    Ah[mt] = ld8(HVh + si); Al[mt] = ld8(HVl + si);
                }
                GEMM_STEP(WvFh, WvFl, (((g * 8 + w) * 16 + kk) * 64 + l) * 8)
            }
            #pragma unroll 2
            for (int kk = 12; kk < 16; ++kk) {
                bf16x8 Ah[4], Al[4];
                #pragma unroll
                for (int mt = 0; mt < 4; ++mt) {
                    const int si = swzHE(mt * 16 + lr, (kk - 12) * 32 + lk * 8);
                    Ah[mt] = ld8(HEh + si); Al[mt] = ld8(HEl + si);
                }
                GEMM_STEP(WvFh, WvFl, (((g * 8 + w) * 16 + kk) * 64 + l) * 8)
            }
            __syncthreads();   // all HE reads done before HE writes
            #pragma unroll
            for (int mt = 0; mt < 4; ++mt)
                #pragma unroll
                for (int r = 0; r < 4; ++r) {
                    const int row = mt * 16 + lk * 4 + r;
                    float gi = sigmoid_f(acc[mt][0][r] + bvi);
                    float gf = sigmoid_f(acc[mt][1][r] + bvf);
                    float gg = tanh_f(acc[mt][2][r] + bvg);
                    float go = sigmoid_f(acc[mt][3][r] + bvo);
                    float cn = gf * ce[mt][r] + gi * gg;
                    ce[mt][r] = cn;
                    float hn = go * tanh_f(cn);
                    u16 hh = f2bf(hn);
                    const int si = swzHE(row, d);
                    HEh[si] = hh; HEl[si] = f2bf(hn - bf2f(hh));
                }
            __syncthreads();   // HE complete before e2v reads
        }
        // ======== edge -> vertex (3 position-specific LSTMs) ========
        #pragma unroll
        for (int p = 0; p < 3; ++p) {
            f32x4 acc[4][4];
            #pragma unroll
            for (int mt = 0; mt < 4; ++mt)
                #pragma unroll
                for (int g = 0; g < 4; ++g) acc[mt][g] = (f32x4)0.0f;

            #pragma unroll 2
            for (int kk = 0; kk < 4; ++kk) {
                bf16x8 Ah[4], Al[4];
                #pragma unroll
                for (int mt = 0; mt < 4; ++mt) {
                    const int si = swzHE(mt * 16 + lr, kk * 32 + lk * 8);
                    Ah[mt] = ld8(HEh + si); Al[mt] = ld8(HEl + si);
                }
                GEMM_STEP(WeFh, WeFl, ((((p * 32) + (g * 8 + w)) * 8 + kk) * 64 + l) * 8)
            }
            #pragma unroll 2
            for (int kk = 4; kk < 8; ++kk) {
                bf16x8 Ah[4], Al[4];
                #pragma unroll
                for (int mt = 0; mt < 4; ++mt) {
                    const int si = swzHV(mt * 16 + lr, p * 128 + (kk - 4) * 32 + lk * 8);
                    Ah[mt] = ld8(HVh + si); Al[mt] = ld8(HVl + si);
                }
                GEMM_STEP(WeFh, WeFl, ((((p * 32) + (g * 8 + w)) * 8 + kk) * 64 + l) * 8)
            }
            __syncthreads();   // all HV[p] reads done before HV[p] writes
            #pragma unroll
            for (int mt = 0; mt < 4; ++mt)
                #pragma unroll
                for (int r = 0; r < 4; ++r) {
                    if ((mbits[p] >> (mt * 4 + r)) & 1u) {
                        const int row = mt * 16 + lk * 4 + r;
                        float gi = sigmoid_f(acc[mt][0][r] + bei[p]);
                        float gf = sigmoid_f(acc[mt][1][r] + bef[p]);
                        float gg = tanh_f(acc[mt][2][r] + beg[p]);
                        float go = sigmoid_f(acc[mt][3][r] + beo[p]);
                        float cn = gf * cv[p][mt][r] + gi * gg;
                        cv[p][mt][r] = cn;
                        float hn = go * tanh_f(cn);
                        u16 hh = f2bf(hn);
                        const int si = swzHV(row, p * 128 + d);
                        HVh[si] = hh; HVl[si] = f2bf(hn - bf2f(hh));
                    }
                }
            // no barrier needed between cell(p) and MFMA(p+1): disjoint LDS regions
        }
        __syncthreads();       // HV[2] writes complete before next v2e (or copy-out)
    }

    // ---- write final h_v (hi/lo) for the projection kernel: [vertex][128] row-major
    for (int i = tid; i < 64 * 48; i += 512) {
        const int row = i / 48, col0 = (i % 48) * 8;
        const int si = swzHV(row, col0);
        const size_t go = (size_t)(e0 + row) * 384 + col0;
        *(u16x8*)&hvOutH[go] = *(const u16x8*)&HVh[si];
        *(u16x8*)&hvOutL[go] = *(const u16x8*)&HVl[si];
    }
#undef GEMM_STEP
}

// logits = h_v @ out_w^T + out_b.  Wave: 32 rows in-register, loops 125 N-tiles.
// 6 independent accumulators (2 row-tiles x 3 split-terms) -> same-acc MFMA distance 6.
__global__ __launch_bounds__(256) void proj_kernel(
    const u16* __restrict__ hvh, const u16* __restrict__ hvl,
    const u16* __restrict__ WFh, const u16* __restrict__ WFl,
    const float* __restrict__ out_b, float* __restrict__ out)
{
    const int tid = threadIdx.x, l = tid & 63;
    const int wid = blockIdx.x * 4 + (tid >> 6);   // 0..3071
    const int r0 = wid * 32;
    const int lr = l & 15, lk = l >> 4;

    bf16x8 Ah[2][4], Al[2][4];
    #pragma unroll
    for (int mt = 0; mt < 2; ++mt)
        #pragma unroll
        for (int kk = 0; kk < 4; ++kk) {
            const int off = (r0 + mt * 16 + lr) * D_ + kk * 32 + lk * 8;
            Ah[mt][kk] = ld8(hvh + off);
            Al[mt][kk] = ld8(hvl + off);
        }

    for (int nt = 0; nt < 125; ++nt) {
        bf16x8 Bh[4], Bl[4];
        #pragma unroll
        for (int kk = 0; kk < 4; ++kk) {
            const int fb = ((nt * 4 + kk) * 64 + l) * 8;
            Bh[kk] = ld8(WFh + fb); Bl[kk] = ld8(WFl + fb);
        }
        f32x4 t0h = (f32x4)0.0f, t0l = (f32x4)0.0f, t0m = (f32x4)0.0f;
        f32x4 t1h = (f32x4)0.0f, t1l = (f32x4)0.0f, t1m = (f32x4)0.0f;
        #pragma unroll
        for (int kk = 0; kk < 4; ++kk) {
            t0h = MF(Ah[0][kk], Bh[kk], t0h);
            t1h = MF(Ah[1][kk], Bh[kk], t1h);
            t0l = MF(Al[0][kk], Bh[kk], t0l);
            t1l = MF(Al[1][kk], Bh[kk], t1l);
            t0m = MF(Ah[0][kk], Bl[kk], t0m);
            t1m = MF(Ah[1][kk], Bl[kk], t1m);
        }
        f32x4 a0 = (t0h + t0l) + t0m;
        f32x4 a1 = (t1h + t1l) + t1m;
        const int n = nt * 16 + lr;
        const float bb = out_b[n];
        #pragma unroll
        for (int r = 0; r < 4; ++r) {
            const size_t row = (size_t)(r0 + lk * 4 + r);
            out[row * VOCAB_ + n] = a0[r] + bb;
            out[(row + 16) * VOCAB_ + n] = a1[r] + bb;
        }
    }
}

extern "C" void kernel_launch(void* const* d_in, const int* in_sizes, int n_in,
                              void* d_out, int out_size, void* d_ws, size_t ws_size,
                              hipStream_t stream)
{
    const int*   x_v     = (const int*)  d_in[0];
    const void*  mask    = d_in[1];
    const float* emb     = (const float*)d_in[2];
    const float* eiw     = (const float*)d_in[3];
    const float* eib     = (const float*)d_in[4];
    const float* Wih_v2e = (const float*)d_in[5];
    const float* Whh_v2e = (const float*)d_in[6];
    const float* bih_v2e = (const float*)d_in[7];
    const float* bhh_v2e = (const float*)d_in[8];
    const float* Wih_e2v = (const float*)d_in[9];
    const float* Whh_e2v = (const float*)d_in[10];
    const float* bih_e2v = (const float*)d_in[11];
    const float* bhh_e2v = (const float*)d_in[12];
    const float* out_w   = (const float*)d_in[13];
    const float* out_b   = (const float*)d_in[14];
    float* out = (float*)d_out;

    // d_ws carve (~54 MB)
    char* ws = (char*)d_ws;
    u16* hvh  = (u16*)(ws);
    u16* hvl  = (u16*)(ws + 25165824);
    u16* WvFh = (u16*)(ws + 50331648);
    u16* WvFl = (u16*)(ws + 50855936);
    u16* WeFh = (u16*)(ws + 51380224);
    u16* WeFl = (u16*)(ws + 52166656);
    u16* OwFh = (u16*)(ws + 52953088);
    u16* OwFl = (u16*)(ws + 53465088);
    float* bv = (float*)(ws + 53977088);
    float* be = (float*)(ws + 53979136);
    int* flag = (int*)(ws + 53985280);

    hipFuncSetAttribute(reinterpret_cast<const void*>(fused_kernel),
                        hipFuncAttributeMaxDynamicSharedMemorySize, 131072);

    hipMemsetAsync(flag, 0, 4, stream);
    detect_mask_kernel<<<16, 256, 0, stream>>>((const unsigned int*)mask, flag);
    prep_kernel<<<3568, 256, 0, stream>>>(Wih_v2e, Whh_v2e, bih_v2e, bhh_v2e,
                                          Wih_e2v, Whh_e2v, bih_e2v, bhh_e2v, out_w,
                                          WvFh, WvFl, WeFh, WeFl, OwFh, OwFl, bv, be);
    fused_kernel<<<E_CNT / 64, 512, 131072, stream>>>(x_v, emb, eiw, eib,
                                                      WvFh, WvFl, WeFh, WeFl, bv, be,
                                                      mask, flag, hvh, hvl);
    proj_kernel<<<768, 256, 0, stream>>>(hvh, hvl, OwFh, OwFl, out_b, out);
}

// Round 5
// 1447.247 us; speedup vs baseline: 1.6869x; 1.6869x over previous
//
#include <hip/hip_runtime.h>

#define E_CNT 32768
#define V_CNT 98304
#define D_ 128
#define VOCAB_ 2000
#define ITERS_ 6

typedef unsigned short u16;
typedef _Float16 f16;
typedef __attribute__((ext_vector_type(8))) _Float16 f16x8;
typedef __attribute__((ext_vector_type(4))) float f32x4;

__device__ __forceinline__ f32x4 MFh(f16x8 a, f16x8 b, f32x4 c) {
    return __builtin_amdgcn_mfma_f32_16x16x32_f16(a, b, c, 0, 0, 0);
}
__device__ __forceinline__ float sigmoid_f(float x) { return 1.0f / (1.0f + __expf(-x)); }
__device__ __forceinline__ float tanh_f(float x) {
    float ax = fabsf(x);
    float t = 1.0f - 2.0f / (__expf(2.0f * ax) + 1.0f);
    return copysignf(t, x);
}

// LDS swizzles (element-unit). h tiles: XOR (row&7)<<3 halfs = 16B granularity ->
// breaks the row-stride ≡ 0 (mod 128B) bank conflict on ds_read_b128.
// CV (f32, scalar access): XOR (row&7)<<2 words -> max 2-way (free).
__device__ __forceinline__ int swzHV(int row, int col) { return (row * 384 + col) ^ ((row & 7) << 3); }
__device__ __forceinline__ int swzHE(int row, int col) { return (row * 128 + col) ^ ((row & 7) << 3); }
__device__ __forceinline__ int cvI(int row, int q)     { return row * 384 + (q ^ ((row & 7) << 2)); }

__global__ void detect_mask_kernel(const unsigned int* __restrict__ m, int* __restrict__ flag) {
    int i = blockIdx.x * 256 + threadIdx.x;
    if (i < 4096 && m[i] > 1u) atomicOr(flag, 1);
}

// Pack weights into MFMA B-fragment order.
// WvF (fp16): [nt(32)][kk(16)][lane(64)][8]  j = nt*16+(l&15), k = kk*32+(l>>4)*8+r
// WeF (fp16): [p(3)][nt(32)][kk(8)][64][8]
// OwF (fp16 hi/lo): [nt(125)][kk(4)][64][8]
__global__ void prep_kernel(
    const float* __restrict__ Wih_v2e, const float* __restrict__ Whh_v2e,
    const float* __restrict__ bih_v2e, const float* __restrict__ bhh_v2e,
    const float* __restrict__ Wih_e2v, const float* __restrict__ Whh_e2v,
    const float* __restrict__ bih_e2v, const float* __restrict__ bhh_e2v,
    const float* __restrict__ out_w,
    f16* __restrict__ WvF, f16* __restrict__ WeF,
    f16* __restrict__ OwFh, f16* __restrict__ OwFl,
    float* __restrict__ bv, float* __restrict__ be)
{
    int idx = blockIdx.x * 256 + threadIdx.x;
    if (idx < 262144) {
        const int r = idx & 7, l = (idx >> 3) & 63, t = idx >> 9;
        const int kk = t & 15, nt = t >> 4;
        const int j = nt * 16 + (l & 15);
        const int k = kk * 32 + (l >> 4) * 8 + r;
        const float w = (k < 384) ? Wih_v2e[j * 384 + k] : Whh_v2e[j * 128 + (k - 384)];
        WvF[idx] = (f16)w;
        return;
    }
    idx -= 262144;
    if (idx < 393216) {
        const int r = idx & 7, l = (idx >> 3) & 63, t = idx >> 9;  // t < 768
        const int kk = t & 7, nt = (t >> 3) & 31, p = t >> 8;
        const int j = nt * 16 + (l & 15);
        const int k = kk * 32 + (l >> 4) * 8 + r;
        const float w = (k < 128) ? Wih_e2v[(p * 512 + j) * 128 + k]
                                  : Whh_e2v[(p * 512 + j) * 128 + (k - 128)];
        WeF[idx] = (f16)w;
        return;
    }
    idx -= 393216;
    if (idx < 256000) {
        const int r = idx & 7, l = (idx >> 3) & 63, t = idx >> 9;  // t < 500
        const int kk = t & 3, nt = t >> 2;
        const int j = nt * 16 + (l & 15);
        const int k = kk * 32 + (l >> 4) * 8 + r;
        const float w = out_w[j * 128 + k];
        const f16 h = (f16)w;
        OwFh[idx] = h;
        OwFl[idx] = (f16)(w - (float)h);
        return;
    }
    idx -= 256000;
    if (idx < 512) { bv[idx] = bih_v2e[idx] + bhh_v2e[idx]; return; }
    idx -= 512;
    if (idx < 1536) { be[idx] = bih_e2v[idx] + bhh_e2v[idx]; return; }
}

// Persistent fused kernel: block = 512 threads (8 waves) owns 64 edges for all 6 iterations.
// LDS (160 KB): HV fp16 [64][384] (48K) + HE fp16 [64][128] (16K) + CV f32 [64][384] (96K).
// c_e stays in registers (16 f32/lane). Wave w owns gate-dim slice d = w*16 + lr for all
// 4 gates (disjoint B columns -> block reads each weight fragment exactly once per iter).
// Live regs ~130 (acc 64 + ce 16 + A 16 + B 4 + misc) -> no bulk c-state spills (round-3/4 bug).
__global__ __launch_bounds__(512) __attribute__((amdgpu_waves_per_eu(2)))
void fused_kernel(
    const int* __restrict__ x_v,
    const float* __restrict__ emb,
    const float* __restrict__ eiw, const float* __restrict__ eib,
    const f16* __restrict__ WvF, const f16* __restrict__ WeF,
    const float* __restrict__ bv, const float* __restrict__ be,
    const void* __restrict__ mask, const int* __restrict__ flagp,
    f16* __restrict__ hvOut)
{
    extern __shared__ char lds[];
    f16*   HV = (f16*)lds;                 // 24576 halfs
    f16*   HE = (f16*)(lds + 49152);       // 8192 halfs
    float* CV = (float*)(lds + 65536);     // 24576 floats

    const int tid = threadIdx.x;
    const int w = tid >> 6, l = tid & 63;
    const int lr = l & 15, lk = l >> 4;
    const int e0 = blockIdx.x * 64;

    // ---- init h_v from embeddings (fp16 into LDS)
    for (int i = tid; i < 64 * 48; i += 512) {
        const int row = i / 48, seg = i % 48;
        const int col0 = seg * 8;
        int id = x_v[(e0 + row) * 3 + (col0 >> 7)];
        if (id < 0 || id > VOCAB_) id = VOCAB_;
        const float* s = emb + id * D_ + (col0 & 127);
        float4 a = *(const float4*)s, b = *(const float4*)(s + 4);
        f16x8 H;
        H[0] = (f16)a.x; H[1] = (f16)a.y; H[2] = (f16)a.z; H[3] = (f16)a.w;
        H[4] = (f16)b.x; H[5] = (f16)b.y; H[6] = (f16)b.z; H[7] = (f16)b.w;
        *(f16x8*)&HV[swzHV(row, col0)] = H;
    }
    // ---- init h_e (same vector for every edge) and CV = 0
    for (int i = tid; i < 64 * 16; i += 512) {
        const int row = i / 16, col0 = (i % 16) * 8;
        f16x8 H;
        #pragma unroll
        for (int j = 0; j < 8; ++j) H[j] = (f16)(eiw[col0 + j] + eib[col0 + j]);
        *(f16x8*)&HE[swzHE(row, col0)] = H;
    }
    for (int i = tid; i < 24576; i += 512) CV[i] = 0.0f;   // swizzle is a per-row bijection

    // ---- per-lane constants: mask bits, c_e state
    const int isByte = *flagp;
    unsigned mbits[3];
    #pragma unroll
    for (int p = 0; p < 3; ++p) {
        unsigned mb = 0;
        #pragma unroll
        for (int mt = 0; mt < 4; ++mt)
            #pragma unroll
            for (int r = 0; r < 4; ++r) {
                const int v = (e0 + mt * 16 + lk * 4 + r) * 3 + p;
                const bool m = isByte ? (((const unsigned char*)mask)[v] != 0)
                                      : (((const int*)mask)[v] != 0);
                mb |= (unsigned)m << (mt * 4 + r);
            }
        mbits[p] = mb;
    }
    const int d = w * 16 + lr;
    float ce[4][4];
    #pragma unroll
    for (int mt = 0; mt < 4; ++mt)
        #pragma unroll
        for (int r = 0; r < 4; ++r) ce[mt][r] = 0.0f;

    __syncthreads();

#define GEMM_STEP(WF, FBASE)                                                  \
    { _Pragma("unroll")                                                       \
      for (int g = 0; g < 4; ++g) {                                           \
          f16x8 B = *(const f16x8*)((WF) + (FBASE));                          \
          _Pragma("unroll")                                                   \
          for (int mt = 0; mt < 4; ++mt) acc[mt][g] = MFh(Ah[mt], B, acc[mt][g]); \
      } }

    #pragma unroll 1
    for (int it = 0; it < ITERS_; ++it) {
        // ======== vertex -> edge ========
        {
            f32x4 acc[4][4];
            #pragma unroll
            for (int mt = 0; mt < 4; ++mt)
                #pragma unroll
                for (int g = 0; g < 4; ++g) acc[mt][g] = (f32x4)0.0f;

            #pragma unroll 2
            for (int kk = 0; kk < 12; ++kk) {
                f16x8 Ah[4];
                #pragma unroll
                for (int mt = 0; mt < 4; ++mt)
                    Ah[mt] = *(const f16x8*)&HV[swzHV(mt * 16 + lr, kk * 32 + lk * 8)];
                GEMM_STEP(WvF, (((g * 8 + w) * 16 + kk) * 64 + l) * 8)
            }
            #pragma unroll 2
            for (int kk = 12; kk < 16; ++kk) {
                f16x8 Ah[4];
                #pragma unroll
                for (int mt = 0; mt < 4; ++mt)
                    Ah[mt] = *(const f16x8*)&HE[swzHE(mt * 16 + lr, (kk - 12) * 32 + lk * 8)];
                GEMM_STEP(WvF, (((g * 8 + w) * 16 + kk) * 64 + l) * 8)
            }
            __syncthreads();   // all HE reads done before HE writes
            const float bvi = bv[d], bvf = bv[128 + d], bvg = bv[256 + d], bvo = bv[384 + d];
            #pragma unroll
            for (int mt = 0; mt < 4; ++mt)
                #pragma unroll
                for (int r = 0; r < 4; ++r) {
                    const int row = mt * 16 + lk * 4 + r;
                    float gi = sigmoid_f(acc[mt][0][r] + bvi);
                    float gf = sigmoid_f(acc[mt][1][r] + bvf);
                    float gg = tanh_f(acc[mt][2][r] + bvg);
                    float go = sigmoid_f(acc[mt][3][r] + bvo);
                    float cn = gf * ce[mt][r] + gi * gg;
                    ce[mt][r] = cn;
                    HE[swzHE(row, d)] = (f16)(go * tanh_f(cn));
                }
            __syncthreads();   // HE complete before e2v reads
        }
        // ======== edge -> vertex (3 position-specific LSTMs) ========
        #pragma unroll
        for (int p = 0; p < 3; ++p) {
            f32x4 acc[4][4];
            #pragma unroll
            for (int mt = 0; mt < 4; ++mt)
                #pragma unroll
                for (int g = 0; g < 4; ++g) acc[mt][g] = (f32x4)0.0f;

            #pragma unroll 2
            for (int kk = 0; kk < 4; ++kk) {
                f16x8 Ah[4];
                #pragma unroll
                for (int mt = 0; mt < 4; ++mt)
                    Ah[mt] = *(const f16x8*)&HE[swzHE(mt * 16 + lr, kk * 32 + lk * 8)];
                GEMM_STEP(WeF, ((((p * 32) + (g * 8 + w)) * 8 + kk) * 64 + l) * 8)
            }
            #pragma unroll 2
            for (int kk = 4; kk < 8; ++kk) {
                f16x8 Ah[4];
                #pragma unroll
                for (int mt = 0; mt < 4; ++mt)
                    Ah[mt] = *(const f16x8*)&HV[swzHV(mt * 16 + lr, p * 128 + (kk - 4) * 32 + lk * 8)];
                GEMM_STEP(WeF, ((((p * 32) + (g * 8 + w)) * 8 + kk) * 64 + l) * 8)
            }
            __syncthreads();   // all HV[p]/HE reads done before HV[p] writes
            const float bei = be[p * 512 + d], bef = be[p * 512 + 128 + d];
            const float beg = be[p * 512 + 256 + d], beo = be[p * 512 + 384 + d];
            #pragma unroll
            for (int mt = 0; mt < 4; ++mt)
                #pragma unroll
                for (int r = 0; r < 4; ++r) {
                    if ((mbits[p] >> (mt * 4 + r)) & 1u) {
                        const int row = mt * 16 + lk * 4 + r;
                        float gi = sigmoid_f(acc[mt][0][r] + bei);
                        float gf = sigmoid_f(acc[mt][1][r] + bef);
                        float gg = tanh_f(acc[mt][2][r] + beg);
                        float go = sigmoid_f(acc[mt][3][r] + beo);
                        const int ci = cvI(row, p * 128 + d);
                        float cn = gf * CV[ci] + gi * gg;
                        CV[ci] = cn;
                        HV[swzHV(row, p * 128 + d)] = (f16)(go * tanh_f(cn));
                    }
                }
            // no barrier between cell(p) and GEMM(p+1): disjoint LDS regions
        }
        __syncthreads();       // HV writes complete before next v2e (or copy-out)
    }

    // ---- write final h_v (fp16) for the projection kernel: [vertex][128] row-major
    for (int i = tid; i < 64 * 48; i += 512) {
        const int row = i / 48, col0 = (i % 48) * 8;
        *(f16x8*)&hvOut[(size_t)(e0 + row) * 384 + col0] = *(const f16x8*)&HV[swzHV(row, col0)];
    }
#undef GEMM_STEP
}

// logits = h_v @ out_w^T + out_b.  Wave: 32 rows in-register, loops 125 N-tiles.
// A single fp16, B fp16 hi/lo (2 terms); 4 independent accumulators.
__global__ __launch_bounds__(256) void proj_kernel(
    const f16* __restrict__ hv,
    const f16* __restrict__ WFh, const f16* __restrict__ WFl,
    const float* __restrict__ out_b, float* __restrict__ out)
{
    const int tid = threadIdx.x, l = tid & 63;
    const int wid = blockIdx.x * 4 + (tid >> 6);   // 0..3071
    const int r0 = wid * 32;
    const int lr = l & 15, lk = l >> 4;

    f16x8 Ah[2][4];
    #pragma unroll
    for (int mt = 0; mt < 2; ++mt)
        #pragma unroll
        for (int kk = 0; kk < 4; ++kk)
            Ah[mt][kk] = *(const f16x8*)(hv + (r0 + mt * 16 + lr) * D_ + kk * 32 + lk * 8);

    for (int nt = 0; nt < 125; ++nt) {
        f16x8 Bh[4], Bl[4];
        #pragma unroll
        for (int kk = 0; kk < 4; ++kk) {
            const int fb = ((nt * 4 + kk) * 64 + l) * 8;
            Bh[kk] = *(const f16x8*)(WFh + fb);
            Bl[kk] = *(const f16x8*)(WFl + fb);
        }
        f32x4 t0 = (f32x4)0.0f, t1 = (f32x4)0.0f, u0 = (f32x4)0.0f, u1 = (f32x4)0.0f;
        #pragma unroll
        for (int kk = 0; kk < 4; ++kk) {
            t0 = MFh(Ah[0][kk], Bh[kk], t0);
            t1 = MFh(Ah[1][kk], Bh[kk], t1);
            u0 = MFh(Ah[0][kk], Bl[kk], u0);
            u1 = MFh(Ah[1][kk], Bl[kk], u1);
        }
        f32x4 a0 = t0 + u0;
        f32x4 a1 = t1 + u1;
        const int n = nt * 16 + lr;
        const float bb = out_b[n];
        #pragma unroll
        for (int r = 0; r < 4; ++r) {
            const size_t row = (size_t)(r0 + lk * 4 + r);
            out[row * VOCAB_ + n] = a0[r] + bb;
            out[(row + 16) * VOCAB_ + n] = a1[r] + bb;
        }
    }
}

extern "C" void kernel_launch(void* const* d_in, const int* in_sizes, int n_in,
                              void* d_out, int out_size, void* d_ws, size_t ws_size,
                              hipStream_t stream)
{
    const int*   x_v     = (const int*)  d_in[0];
    const void*  mask    = d_in[1];
    const float* emb     = (const float*)d_in[2];
    const float* eiw     = (const float*)d_in[3];
    const float* eib     = (const float*)d_in[4];
    const float* Wih_v2e = (const float*)d_in[5];
    const float* Whh_v2e = (const float*)d_in[6];
    const float* bih_v2e = (const float*)d_in[7];
    const float* bhh_v2e = (const float*)d_in[8];
    const float* Wih_e2v = (const float*)d_in[9];
    const float* Whh_e2v = (const float*)d_in[10];
    const float* bih_e2v = (const float*)d_in[11];
    const float* bhh_e2v = (const float*)d_in[12];
    const float* out_w   = (const float*)d_in[13];
    const float* out_b   = (const float*)d_in[14];
    float* out = (float*)d_out;

    // d_ws carve (~27.5 MB)
    char* ws = (char*)d_ws;
    f16*   hv   = (f16*)(ws);                  // 25165824 B
    f16*   WvF  = (f16*)(ws + 25165824);       // 524288
    f16*   WeF  = (f16*)(ws + 25690112);       // 786432
    f16*   OwFh = (f16*)(ws + 26476544);       // 512000
    f16*   OwFl = (f16*)(ws + 26988544);       // 512000
    float* bv   = (float*)(ws + 27500544);     // 2048
    float* be   = (float*)(ws + 27502592);     // 6144
    int*   flag = (int*)(ws + 27508736);

    hipFuncSetAttribute(reinterpret_cast<const void*>(fused_kernel),
                        hipFuncAttributeMaxDynamicSharedMemorySize, 163840);

    hipMemsetAsync(flag, 0, 4, stream);
    detect_mask_kernel<<<16, 256, 0, stream>>>((const unsigned int*)mask, flag);
    prep_kernel<<<3568, 256, 0, stream>>>(Wih_v2e, Whh_v2e, bih_v2e, bhh_v2e,
                                          Wih_e2v, Whh_e2v, bih_e2v, bhh_e2v, out_w,
                                          WvF, WeF, OwFh, OwFl, bv, be);
    fused_kernel<<<E_CNT / 64, 512, 163840, stream>>>(x_v, emb, eiw, eib,
                                                      WvF, WeF, bv, be,
                                                      mask, flag, hv);
    proj_kernel<<<768, 256, 0, stream>>>(hv, OwFh, OwFl, out_b, out);
}